// Round 1
// baseline (221.805 us; speedup 1.0000x reference)
//
#include <hip/hip_runtime.h>

// Problem constants (from setup_inputs: B=16, O=8192, K1=5, D=64, n_samples=2048)
#define K1 5
#define DIM 64
#define OCNT 8192
#define NS 2048
#define BLOCK 256

__device__ __forceinline__ double det4(const double m[4][4]) {
    // Laplace expansion along row 0 using 2x2 minors of rows 2,3
    double c01 = m[2][0] * m[3][1] - m[2][1] * m[3][0];
    double c02 = m[2][0] * m[3][2] - m[2][2] * m[3][0];
    double c03 = m[2][0] * m[3][3] - m[2][3] * m[3][0];
    double c12 = m[2][1] * m[3][2] - m[2][2] * m[3][1];
    double c13 = m[2][1] * m[3][3] - m[2][3] * m[3][1];
    double c23 = m[2][2] * m[3][3] - m[2][3] * m[3][2];
    double d0 = m[1][1] * c23 - m[1][2] * c13 + m[1][3] * c12;
    double d1 = m[1][0] * c23 - m[1][2] * c03 + m[1][3] * c02;
    double d2 = m[1][0] * c13 - m[1][1] * c03 + m[1][3] * c01;
    double d3 = m[1][0] * c12 - m[1][1] * c02 + m[1][2] * c01;
    return m[0][0] * d0 - m[0][1] * d1 + m[0][2] * d2 - m[0][3] * d3;
}

__global__ __launch_bounds__(BLOCK) void cm_main_kernel(
        const float* __restrict__ pts,    // [B, O, K1, DIM]
        const int* __restrict__ sidx,     // [B, NS]
        float* __restrict__ block_sums) { // [gridDim.x]
    const int t = blockIdx.x * BLOCK + threadIdx.x;   // simplex id in [0, 32768)
    const int b = t >> 11;                            // / NS (2048)
    const int o = sidx[t];
    const float* base = pts + ((size_t)b * OCNT + (size_t)o) * (K1 * DIM);

    // ---- Gram matrix accumulation: 15 unique entries (i<=j) ----
    float acc[15];
#pragma unroll
    for (int i = 0; i < 15; ++i) acc[i] = 0.0f;

#pragma unroll
    for (int d0 = 0; d0 < DIM; d0 += 4) {
        float4 x[K1];
#pragma unroll
        for (int i = 0; i < K1; ++i)
            x[i] = *reinterpret_cast<const float4*>(base + i * DIM + d0);
        const float* xf = reinterpret_cast<const float*>(x);  // xf[i*4 + c]
#pragma unroll
        for (int c = 0; c < 4; ++c) {
            float y0 = xf[0 * 4 + c], y1 = xf[1 * 4 + c], y2 = xf[2 * 4 + c],
                  y3 = xf[3 * 4 + c], y4 = xf[4 * 4 + c];
            acc[0]  = fmaf(y0, y0, acc[0]);
            acc[1]  = fmaf(y0, y1, acc[1]);
            acc[2]  = fmaf(y0, y2, acc[2]);
            acc[3]  = fmaf(y0, y3, acc[3]);
            acc[4]  = fmaf(y0, y4, acc[4]);
            acc[5]  = fmaf(y1, y1, acc[5]);
            acc[6]  = fmaf(y1, y2, acc[6]);
            acc[7]  = fmaf(y1, y3, acc[7]);
            acc[8]  = fmaf(y1, y4, acc[8]);
            acc[9]  = fmaf(y2, y2, acc[9]);
            acc[10] = fmaf(y2, y3, acc[10]);
            acc[11] = fmaf(y2, y4, acc[11]);
            acc[12] = fmaf(y3, y3, acc[12]);
            acc[13] = fmaf(y3, y4, acc[13]);
            acc[14] = fmaf(y4, y4, acc[14]);
        }
    }

    float G[K1][K1];
    {
        int k = 0;
#pragma unroll
        for (int i = 0; i < K1; ++i)
#pragma unroll
            for (int j = i; j < K1; ++j) {
                G[i][j] = acc[k];
                G[j][i] = acc[k];
                ++k;
            }
    }

    // Row sums and total
    float S[K1];
    float T = 0.0f;
#pragma unroll
    for (int i = 0; i < K1; ++i) {
        S[i] = G[i][0] + G[i][1] + G[i][2] + G[i][3] + G[i][4];
        T += S[i];
    }
    float ci[K1];
#pragma unroll
    for (int i = 0; i < K1; ++i) ci[i] = S[i] * 0.2f;    // v_i . centroid
    const float cc = T * 0.04f;                          // ||centroid||^2

    // ---- rose score ----
    float nrm[K1];
#pragma unroll
    for (int i = 0; i < K1; ++i) {
        float r2 = G[i][i] - 2.0f * ci[i] + cc;          // ||v_i - c||^2
        r2 = fmaxf(r2, 0.0f);
        nrm[i] = fmaxf(sqrtf(r2), 1e-8f);                // clip(norm, EPS)
    }
    float sumcos = 0.0f;
#pragma unroll
    for (int i = 0; i < K1; ++i)
#pragma unroll
        for (int j = i + 1; j < K1; ++j) {
            float num = G[i][j] - ci[i] - ci[j] + cc;    // rad_i . rad_j
            sumcos += num / (nrm[i] * nrm[j]);
        }
    // cos_mean = 2*sumcos / (n*(n-1)) = sumcos / 10
    const float rose = (sumcos * 0.1f + 1.0f) * 0.5f;

    // ---- regularity ----
    float dmin = 3.4e38f, dmax = 0.0f;
#pragma unroll
    for (int i = 0; i < K1; ++i)
#pragma unroll
        for (int j = i + 1; j < K1; ++j) {
            float d2 = G[i][i] + G[j][j] - 2.0f * G[i][j];
            float dd = sqrtf(fmaxf(d2, 1e-12f));
            dmin = fminf(dmin, dd);
            dmax = fmaxf(dmax, dd);
        }
    const float reg = dmin / fmaxf(dmax, 1e-8f);

    // ---- Cayley-Menger volume via edge-Gram determinant ----
    // W[a][c] = (v_a - v_0) . (v_c - v_0), a,c = 1..4
    // CM 6x6 det == -16 * det(W); v2 = coeff*det = det(W)/576; vol = sqrt(det(W))/24
    double W[4][4];
#pragma unroll
    for (int a = 1; a < K1; ++a)
#pragma unroll
        for (int c = 1; c < K1; ++c)
            W[a - 1][c - 1] =
                (double)G[a][c] - (double)G[a][0] - (double)G[0][c] + (double)G[0][0];
    double dW = det4(W);
    double vol = sqrt(fmax(dW, 0.0)) * (1.0 / 24.0);
    const float degen = (vol < 1e-8) ? 1.0f : 0.0f;

    float loss = 0.5f * (1.0f - rose) + 0.3f * (1.0f - reg) + 0.2f * degen;

    // ---- block reduction ----
#pragma unroll
    for (int off = 32; off > 0; off >>= 1)
        loss += __shfl_down(loss, off, 64);
    __shared__ float wsum[BLOCK / 64];
    const int lane = threadIdx.x & 63;
    const int wave = threadIdx.x >> 6;
    if (lane == 0) wsum[wave] = loss;
    __syncthreads();
    if (threadIdx.x == 0) {
        float s = 0.0f;
#pragma unroll
        for (int w = 0; w < BLOCK / 64; ++w) s += wsum[w];
        block_sums[blockIdx.x] = s;
    }
}

__global__ __launch_bounds__(128) void cm_final_kernel(
        const float* __restrict__ block_sums, float* __restrict__ out,
        int nblocks, float inv_n) {
    float v = (threadIdx.x < (unsigned)nblocks) ? block_sums[threadIdx.x] : 0.0f;
#pragma unroll
    for (int off = 32; off > 0; off >>= 1)
        v += __shfl_down(v, off, 64);
    __shared__ float wsum[2];
    const int lane = threadIdx.x & 63;
    const int wave = threadIdx.x >> 6;
    if (lane == 0) wsum[wave] = v;
    __syncthreads();
    if (threadIdx.x == 0) out[0] = (wsum[0] + wsum[1]) * inv_n;
}

extern "C" void kernel_launch(void* const* d_in, const int* in_sizes, int n_in,
                              void* d_out, int out_size, void* d_ws, size_t ws_size,
                              hipStream_t stream) {
    const float* pts = (const float*)d_in[0];   // [16, 8192, 5, 64] f32
    const int* sidx  = (const int*)d_in[1];     // [16, 2048] i32
    float* out = (float*)d_out;                 // scalar f32
    float* block_sums = (float*)d_ws;

    const int nsimp = in_sizes[1];              // 32768
    const int nblocks = nsimp / BLOCK;          // 128

    cm_main_kernel<<<nblocks, BLOCK, 0, stream>>>(pts, sidx, block_sums);
    cm_final_kernel<<<1, 128, 0, stream>>>(block_sums, out, nblocks,
                                           1.0f / (float)nsimp);
}

// Round 2
// 209.310 us; speedup vs baseline: 1.0597x; 1.0597x over previous
//
#include <hip/hip_runtime.h>

// Problem constants (from setup_inputs: B=16, O=8192, K1=5, D=64, n_samples=2048)
#define K1 5
#define DIM 64
#define OCNT 8192
#define NSAMP_PER_B 2048
#define BLOCK 256
#define LANES_PER_SIMPLEX 16   // one quarter-wave per simplex

__device__ __forceinline__ double det4(const double m[4][4]) {
    double c01 = m[2][0] * m[3][1] - m[2][1] * m[3][0];
    double c02 = m[2][0] * m[3][2] - m[2][2] * m[3][0];
    double c03 = m[2][0] * m[3][3] - m[2][3] * m[3][0];
    double c12 = m[2][1] * m[3][2] - m[2][2] * m[3][1];
    double c13 = m[2][1] * m[3][3] - m[2][3] * m[3][1];
    double c23 = m[2][2] * m[3][3] - m[2][3] * m[3][2];
    double d0 = m[1][1] * c23 - m[1][2] * c13 + m[1][3] * c12;
    double d1 = m[1][0] * c23 - m[1][2] * c03 + m[1][3] * c02;
    double d2 = m[1][0] * c13 - m[1][1] * c03 + m[1][3] * c01;
    double d3 = m[1][0] * c12 - m[1][1] * c02 + m[1][2] * c01;
    return m[0][0] * d0 - m[0][1] * d1 + m[0][2] * d2 - m[0][3] * d3;
}

__global__ __launch_bounds__(BLOCK) void cm_main_kernel(
        const float* __restrict__ pts,    // [B, O, K1, DIM] f32
        const int* __restrict__ sidx,     // [B, NSAMP_PER_B] i32
        float* __restrict__ block_sums) { // [gridDim.x]
    const int tid = blockIdx.x * BLOCK + threadIdx.x;
    const int t = tid >> 4;                    // simplex id in [0, 32768)
    const int g = threadIdx.x & 15;            // lane-in-group
    const int b = t >> 11;                     // t / 2048
    const int o = sidx[t];                     // broadcast load within group
    const float* base =
        pts + ((size_t)b * OCNT + (size_t)o) * (K1 * DIM) + g * 4;

    // ---- coalesced load: lane g holds dims [4g..4g+3] of all 5 rows ----
    float4 x[K1];
#pragma unroll
    for (int i = 0; i < K1; ++i)
        x[i] = *reinterpret_cast<const float4*>(base + i * DIM);

    // ---- partial Gram: 15 unique entries (i<=j), 4-dim dot each ----
    float acc[15];
    {
        int k = 0;
#pragma unroll
        for (int i = 0; i < K1; ++i)
#pragma unroll
            for (int j = i; j < K1; ++j) {
                acc[k] = x[i].x * x[j].x + x[i].y * x[j].y +
                         x[i].z * x[j].z + x[i].w * x[j].w;
                ++k;
            }
    }
    // ---- reduce across the 16-lane group (xor masks stay in-group) ----
#pragma unroll
    for (int mask = 1; mask < LANES_PER_SIMPLEX; mask <<= 1) {
#pragma unroll
        for (int k = 0; k < 15; ++k)
            acc[k] += __shfl_xor(acc[k], mask, 64);
    }

    float G[K1][K1];
    {
        int k = 0;
#pragma unroll
        for (int i = 0; i < K1; ++i)
#pragma unroll
            for (int j = i; j < K1; ++j) {
                G[i][j] = acc[k];
                G[j][i] = acc[k];
                ++k;
            }
    }

    // Row sums and total
    float S[K1];
    float T = 0.0f;
#pragma unroll
    for (int i = 0; i < K1; ++i) {
        S[i] = G[i][0] + G[i][1] + G[i][2] + G[i][3] + G[i][4];
        T += S[i];
    }
    float ci[K1];
#pragma unroll
    for (int i = 0; i < K1; ++i) ci[i] = S[i] * 0.2f;    // v_i . centroid
    const float cc = T * 0.04f;                          // ||centroid||^2

    // ---- rose score ----
    float nrm[K1];
#pragma unroll
    for (int i = 0; i < K1; ++i) {
        float r2 = G[i][i] - 2.0f * ci[i] + cc;          // ||v_i - c||^2
        r2 = fmaxf(r2, 0.0f);
        nrm[i] = fmaxf(sqrtf(r2), 1e-8f);
    }
    float sumcos = 0.0f;
#pragma unroll
    for (int i = 0; i < K1; ++i)
#pragma unroll
        for (int j = i + 1; j < K1; ++j) {
            float num = G[i][j] - ci[i] - ci[j] + cc;    // rad_i . rad_j
            sumcos += num / (nrm[i] * nrm[j]);
        }
    const float rose = (sumcos * 0.1f + 1.0f) * 0.5f;    // cos_mean = sumcos/10

    // ---- regularity ----
    float dmin = 3.4e38f, dmax = 0.0f;
#pragma unroll
    for (int i = 0; i < K1; ++i)
#pragma unroll
        for (int j = i + 1; j < K1; ++j) {
            float d2 = G[i][i] + G[j][j] - 2.0f * G[i][j];
            float dd = sqrtf(fmaxf(d2, 1e-12f));
            dmin = fminf(dmin, dd);
            dmax = fmaxf(dmax, dd);
        }
    const float reg = dmin / fmaxf(dmax, 1e-8f);

    // ---- Cayley-Menger volume via edge-Gram determinant ----
    // W[a][c] = (v_a - v_0).(v_c - v_0); CM det == -16*det(W);
    // v2 = det(W)/576; vol = sqrt(det(W))/24
    double W[4][4];
#pragma unroll
    for (int a = 1; a < K1; ++a)
#pragma unroll
        for (int c = 1; c < K1; ++c)
            W[a - 1][c - 1] =
                (double)G[a][c] - (double)G[a][0] - (double)G[0][c] + (double)G[0][0];
    double dW = det4(W);
    double vol = sqrt(fmax(dW, 0.0)) * (1.0 / 24.0);
    const float degen = (vol < 1e-8) ? 1.0f : 0.0f;

    float loss = 0.5f * (1.0f - rose) + 0.3f * (1.0f - reg) + 0.2f * degen;

    // Only one lane per group contributes; full-wave butterfly reduce.
    loss = (g == 0) ? loss : 0.0f;
#pragma unroll
    for (int off = 32; off > 0; off >>= 1)
        loss += __shfl_down(loss, off, 64);

    __shared__ float wsum[BLOCK / 64];
    const int lane = threadIdx.x & 63;
    const int wave = threadIdx.x >> 6;
    if (lane == 0) wsum[wave] = loss;
    __syncthreads();
    if (threadIdx.x == 0) {
        float s = 0.0f;
#pragma unroll
        for (int w = 0; w < BLOCK / 64; ++w) s += wsum[w];
        block_sums[blockIdx.x] = s;
    }
}

__global__ __launch_bounds__(BLOCK) void cm_final_kernel(
        const float* __restrict__ block_sums, float* __restrict__ out,
        int nblocks, float inv_n) {
    float v = 0.0f;
    for (int i = threadIdx.x; i < nblocks; i += BLOCK) v += block_sums[i];
#pragma unroll
    for (int off = 32; off > 0; off >>= 1)
        v += __shfl_down(v, off, 64);
    __shared__ float wsum[BLOCK / 64];
    const int lane = threadIdx.x & 63;
    const int wave = threadIdx.x >> 6;
    if (lane == 0) wsum[wave] = v;
    __syncthreads();
    if (threadIdx.x == 0) {
        float s = 0.0f;
#pragma unroll
        for (int w = 0; w < BLOCK / 64; ++w) s += wsum[w];
        out[0] = s * inv_n;
    }
}

extern "C" void kernel_launch(void* const* d_in, const int* in_sizes, int n_in,
                              void* d_out, int out_size, void* d_ws, size_t ws_size,
                              hipStream_t stream) {
    const float* pts = (const float*)d_in[0];   // [16, 8192, 5, 64] f32
    const int* sidx  = (const int*)d_in[1];     // [16, 2048] i32
    float* out = (float*)d_out;                 // scalar f32
    float* block_sums = (float*)d_ws;

    const int nsimp = in_sizes[1];                          // 32768
    const int nblocks = nsimp * LANES_PER_SIMPLEX / BLOCK;  // 2048

    cm_main_kernel<<<nblocks, BLOCK, 0, stream>>>(pts, sidx, block_sums);
    cm_final_kernel<<<1, BLOCK, 0, stream>>>(block_sums, out, nblocks,
                                             1.0f / (float)nsimp);
}